// Round 14
// baseline (65.109 us; speedup 1.0000x reference)
//
#include <hip/hip_runtime.h>
#include <hip/hip_bf16.h>

#define EMB_DIM 512
#define B_SZ 1024
#define LT 50
#define LD 200
#define H_D 1024
#define K_FC 2048   // 4*EMB_DIM
#define NCLS 10
#define BN_EPS 1e-5f
#define NEGV -1e30f

typedef short short8 __attribute__((ext_vector_type(8)));
typedef float f32x4 __attribute__((ext_vector_type(4)));

// XOR swizzle: spread row-stride reads across banks (guide §6 G4)
#define SWZ(r, b) ((b) ^ (((r) & 7) << 4))

#define ACC4(S, M, E) \
  S.x += E.x; S.y += E.y; S.z += E.z; S.w += E.w; \
  M.x = fmaxf(M.x, E.x); M.y = fmaxf(M.y, E.y); \
  M.z = fmaxf(M.z, E.z); M.w = fmaxf(M.w, E.w);

// ---------------- Kernel 1: fused SWEM pool + transposes ------------------
// Pool: 4-stream pipelined gather (R13 version, best measured).
__global__ __launch_bounds__(512) void pool_tr_kernel(
    const int* __restrict__ title, const int* __restrict__ desc,
    const int* __restrict__ t_len, const int* __restrict__ d_len,
    const float* __restrict__ emb, __hip_bfloat16* __restrict__ swem,
    const float* __restrict__ W, __hip_bfloat16* __restrict__ Wt,
    const float* __restrict__ Wclf, float* __restrict__ WclfT) {
  __shared__ float sm[8192];
  __shared__ int idxs[264];

  const int bid = blockIdx.x;
  const int tid = threadIdx.x;

  if (bid >= 2 * B_SZ) {
    const int t = bid - 2 * B_SZ;
    if (t == 512) {
      for (int idx = tid; idx < NCLS * H_D; idx += 512) {
        int j = idx >> 10, k = idx & 1023;
        WclfT[j * H_D + k] = Wclf[(size_t)k * NCLS + j];
      }
      return;
    }
    const int n0 = (t & 15) * 64;
    const int k0 = (t >> 4) * 64;
#pragma unroll
    for (int i = 0; i < 8; ++i) {
      int idx = i * 512 + tid;
      int r = idx >> 6, c = idx & 63;
      sm[r * 65 + c] = W[(size_t)(k0 + r) * H_D + n0 + c];
    }
    __syncthreads();
#pragma unroll
    for (int i = 0; i < 8; ++i) {
      int idx = i * 512 + tid;
      int r = idx >> 6, c = idx & 63;
      Wt[(size_t)(n0 + r) * K_FC + k0 + c] = __float2bfloat16(sm[c * 65 + r]);
    }
    return;
  }

  const int b = bid >> 1;
  const int half = bid & 1;
  const int wave = tid >> 6;
  const int lane = tid & 63;
  const int dbase = half * 256 + lane * 4;

  if (tid < LT) idxs[tid] = title[b * LT + tid];
  else if (tid >= 64 && tid < 64 + LD) idxs[tid] = desc[b * LD + tid - 64];
  const int tl = t_len[b];
  const int dl = d_len[b];
  __syncthreads();

#define LOADT(IDXOFF, I) \
  (*reinterpret_cast<const float4*>(emb + (size_t)idxs[(IDXOFF) + wave + (I) * 8] * EMB_DIM + dbase))

#define POOL_LIST(LEN, IDXOFF, SARR, MARR)                                         \
  {                                                                                \
    float4 s0 = make_float4(0.f, 0.f, 0.f, 0.f), s1 = s0, s2 = s0, s3 = s0;        \
    float4 m0 = make_float4(NEGV, NEGV, NEGV, NEGV), m1 = m0, m2 = m0, m3 = m0;    \
    const int cnt = (LEN > wave) ? ((LEN - wave + 7) >> 3) : 0;                    \
    int i = 0;                                                                     \
    if (cnt >= 4) {                                                                \
      float4 e0 = LOADT(IDXOFF, 0); float4 e1 = LOADT(IDXOFF, 1);                  \
      float4 e2 = LOADT(IDXOFF, 2); float4 e3 = LOADT(IDXOFF, 3);                  \
      i = 4;                                                                       \
      for (; i + 3 < cnt; i += 4) {                                                \
        float4 q0 = LOADT(IDXOFF, i);     float4 q1 = LOADT(IDXOFF, i + 1);        \
        float4 q2 = LOADT(IDXOFF, i + 2); float4 q3 = LOADT(IDXOFF, i + 3);        \
        ACC4(s0, m0, e0); ACC4(s1, m1, e1); ACC4(s2, m2, e2); ACC4(s3, m3, e3);    \
        e0 = q0; e1 = q1; e2 = q2; e3 = q3;                                        \
      }                                                                            \
      ACC4(s0, m0, e0); ACC4(s1, m1, e1); ACC4(s2, m2, e2); ACC4(s3, m3, e3);      \
    }                                                                              \
    for (; i < cnt; ++i) { float4 t2 = LOADT(IDXOFF, i); ACC4(s0, m0, t2); }       \
    s0.x += s1.x + s2.x + s3.x; s0.y += s1.y + s2.y + s3.y;                        \
    s0.z += s1.z + s2.z + s3.z; s0.w += s1.w + s2.w + s3.w;                        \
    m0.x = fmaxf(fmaxf(m0.x, m1.x), fmaxf(m2.x, m3.x));                            \
    m0.y = fmaxf(fmaxf(m0.y, m1.y), fmaxf(m2.y, m3.y));                            \
    m0.z = fmaxf(fmaxf(m0.z, m1.z), fmaxf(m2.z, m3.z));                            \
    m0.w = fmaxf(fmaxf(m0.w, m1.w), fmaxf(m2.w, m3.w));                            \
    *reinterpret_cast<float4*>(&sm[(SARR * 8 + wave) * 256 + lane * 4]) = s0;      \
    *reinterpret_cast<float4*>(&sm[(MARR * 8 + wave) * 256 + lane * 4]) = m0;      \
  }

  POOL_LIST(tl, 0, 0, 1)
  POOL_LIST(dl, 64, 2, 3)

  __syncthreads();

  if (tid < 64) {
    const float it = 1.0f / (float)tl;
    const float id = 1.0f / (float)dl;
    float4 ts = make_float4(0.f, 0.f, 0.f, 0.f);
    float4 tm = make_float4(NEGV, NEGV, NEGV, NEGV);
    float4 ds = make_float4(0.f, 0.f, 0.f, 0.f);
    float4 dm = make_float4(NEGV, NEGV, NEGV, NEGV);
#pragma unroll
    for (int w = 0; w < 8; ++w) {
      float4 a = *reinterpret_cast<const float4*>(&sm[(0 * 8 + w) * 256 + tid * 4]);
      ts.x += a.x; ts.y += a.y; ts.z += a.z; ts.w += a.w;
      float4 bmx = *reinterpret_cast<const float4*>(&sm[(1 * 8 + w) * 256 + tid * 4]);
      tm.x = fmaxf(tm.x, bmx.x); tm.y = fmaxf(tm.y, bmx.y);
      tm.z = fmaxf(tm.z, bmx.z); tm.w = fmaxf(tm.w, bmx.w);
      float4 c = *reinterpret_cast<const float4*>(&sm[(2 * 8 + w) * 256 + tid * 4]);
      ds.x += c.x; ds.y += c.y; ds.z += c.z; ds.w += c.w;
      float4 dmx = *reinterpret_cast<const float4*>(&sm[(3 * 8 + w) * 256 + tid * 4]);
      dm.x = fmaxf(dm.x, dmx.x); dm.y = fmaxf(dm.y, dmx.y);
      dm.z = fmaxf(dm.z, dmx.z); dm.w = fmaxf(dm.w, dmx.w);
    }
    __hip_bfloat16* row = swem + (size_t)b * K_FC + half * 256 + tid * 4;
    union { ushort4 v; __hip_bfloat16 h[4]; } u;
    u.h[0] = __float2bfloat16(ts.x * it); u.h[1] = __float2bfloat16(ts.y * it);
    u.h[2] = __float2bfloat16(ts.z * it); u.h[3] = __float2bfloat16(ts.w * it);
    *reinterpret_cast<ushort4*>(&row[0 * EMB_DIM]) = u.v;
    u.h[0] = __float2bfloat16(tm.x); u.h[1] = __float2bfloat16(tm.y);
    u.h[2] = __float2bfloat16(tm.z); u.h[3] = __float2bfloat16(tm.w);
    *reinterpret_cast<ushort4*>(&row[1 * EMB_DIM]) = u.v;
    u.h[0] = __float2bfloat16(ds.x * id); u.h[1] = __float2bfloat16(ds.y * id);
    u.h[2] = __float2bfloat16(ds.z * id); u.h[3] = __float2bfloat16(ds.w * id);
    *reinterpret_cast<ushort4*>(&row[2 * EMB_DIM]) = u.v;
    u.h[0] = __float2bfloat16(dm.x); u.h[1] = __float2bfloat16(dm.y);
    u.h[2] = __float2bfloat16(dm.z); u.h[3] = __float2bfloat16(dm.w);
    *reinterpret_cast<ushort4*>(&row[3 * EMB_DIM]) = u.v;
  }
}

// ---------------- Kernel 2: MFMA GEMM v8 (BK=128) --------------------------
// 64x64 tile, 256 blocks XCD-swizzled, 512 threads, dbuf LDS (2x32KB),
// reg prefetch depth 2, BK=128: 16 iterations (half the barriers of BK=64),
// 8 MFMA/wave/iter (longer shadow over in-flight loads).
__global__ __launch_bounds__(512) void gemm_mfma_kernel(
    const __hip_bfloat16* __restrict__ A,   // [1024][2048] bf16 (swem)
    const __hip_bfloat16* __restrict__ Bt,  // [1024][2048] bf16 (W_fc^T)
    const float* __restrict__ bias, float* __restrict__ C,
    float* __restrict__ psum, float* __restrict__ psq) {
  __shared__ unsigned char As[2][16384];   // 64 rows x 256B
  __shared__ unsigned char Bs[2][16384];
  __shared__ float reds[2][4][16];  // [wr][wc][lo]
  __shared__ float redq[2][4][16];
  const int tid = threadIdx.x;
  const int lane = tid & 63;
  const int wave = tid >> 6;        // 0..7
  const int wr = wave >> 2;         // 0,1  (M)
  const int wc = wave & 3;          // 0..3 (N)

  const int lin = blockIdx.y * 16 + blockIdx.x;
  const int swzb = (lin & 7) * 32 + (lin >> 3);
  const int bx = swzb & 15, by = swzb >> 4;
  const int m0 = by * 64, n0 = bx * 64;

  f32x4 acc[2] = {};                // mi = 0,1

  // staging: 1024 chunks of 16B per matrix per tile; 2 chunks/thread.
  // chunks are (row, slot): row = c>>4 (0..63), slot = c&15 (16B units).
  // tid*2 even -> both chunks share a row, slots s, s+1.
  const int rs = tid >> 3;          // row 0..63
  const int s0 = (tid & 7) * 2;     // even slot 0..14
  const int hi = lane >> 4;
  const int lo = lane & 15;

  const __hip_bfloat16* pa = A + (size_t)(m0 + rs) * K_FC + s0 * 8;
  const __hip_bfloat16* pb = Bt + (size_t)(n0 + rs) * K_FC + s0 * 8;
  const int off0 = SWZ(rs, rs * 256 + s0 * 16);
  const int off1 = SWZ(rs, rs * 256 + (s0 + 1) * 16);

  // prologue: tile 0 -> LDS buf 0; tile 1 -> regs
  float4 a10 = *reinterpret_cast<const float4*>(pa);
  float4 a11 = *reinterpret_cast<const float4*>(pa + 8);
  float4 b10 = *reinterpret_cast<const float4*>(pb);
  float4 b11 = *reinterpret_cast<const float4*>(pb + 8);
  *reinterpret_cast<float4*>(&As[0][off0]) = a10;
  *reinterpret_cast<float4*>(&As[0][off1]) = a11;
  *reinterpret_cast<float4*>(&Bs[0][off0]) = b10;
  *reinterpret_cast<float4*>(&Bs[0][off1]) = b11;
  a10 = *reinterpret_cast<const float4*>(pa + 128);
  a11 = *reinterpret_cast<const float4*>(pa + 136);
  b10 = *reinterpret_cast<const float4*>(pb + 128);
  b11 = *reinterpret_cast<const float4*>(pb + 136);
  __syncthreads();

  int cur = 0;
  for (int k0 = 0; k0 < K_FC; k0 += 128) {
    // issue loads for tile k+2 (fly under the 8-MFMA cluster + barrier)
    float4 an0 = make_float4(0.f, 0.f, 0.f, 0.f), an1 = an0, bn0 = an0, bn1 = an0;
    if (k0 + 256 < K_FC) {
      an0 = *reinterpret_cast<const float4*>(pa + k0 + 256);
      an1 = *reinterpret_cast<const float4*>(pa + k0 + 264);
      bn0 = *reinterpret_cast<const float4*>(pb + k0 + 256);
      bn1 = *reinterpret_cast<const float4*>(pb + k0 + 264);
    }

#pragma unroll
    for (int kks = 0; kks < 4; ++kks) {
      short8 af[2];
#pragma unroll
      for (int mi = 0; mi < 2; ++mi) {
        int r = wr * 32 + mi * 16 + lo;
        af[mi] = *reinterpret_cast<const short8*>(&As[cur][SWZ(r, r * 256 + kks * 64 + hi * 16)]);
      }
      int rb = wc * 16 + lo;
      short8 bf = *reinterpret_cast<const short8*>(&Bs[cur][SWZ(rb, rb * 256 + kks * 64 + hi * 16)]);
#pragma unroll
      for (int mi = 0; mi < 2; ++mi)
        acc[mi] = __builtin_amdgcn_mfma_f32_16x16x32_bf16(af[mi], bf, acc[mi], 0, 0, 0);
    }

    if (k0 + 128 < K_FC) {
      *reinterpret_cast<float4*>(&As[cur ^ 1][off0]) = a10;
      *reinterpret_cast<float4*>(&As[cur ^ 1][off1]) = a11;
      *reinterpret_cast<float4*>(&Bs[cur ^ 1][off0]) = b10;
      *reinterpret_cast<float4*>(&Bs[cur ^ 1][off1]) = b11;
    }
    __syncthreads();
    a10 = an0; a11 = an1; b10 = bn0; b11 = bn1;
    cur ^= 1;
  }

  // epilogue: C write (+bias) and per-column partial sum/sumsq.
  // C/D layout: col=lane&15, row=(lane>>4)*4+reg (m89-verified).
  {
    int col = n0 + wc * 16 + lo;
    float bv = bias[col];
    float s = 0.f, q = 0.f;
#pragma unroll
    for (int mi = 0; mi < 2; ++mi) {
#pragma unroll
      for (int r = 0; r < 4; ++r) {
        float v = acc[mi][r] + bv;
        s += v; q += v * v;
        int rowm = m0 + wr * 32 + mi * 16 + hi * 4 + r;
        C[(size_t)rowm * H_D + col] = v;
      }
    }
    s += __shfl_xor(s, 16);
    s += __shfl_xor(s, 32);
    q += __shfl_xor(q, 16);
    q += __shfl_xor(q, 32);
    if (lane < 16) { reds[wr][wc][lo] = s; redq[wr][wc][lo] = q; }
  }
  __syncthreads();
  if (tid < 64) {
    int wc2 = tid >> 4, lo2 = tid & 15;
    float s = reds[0][wc2][lo2] + reds[1][wc2][lo2];
    float q = redq[0][wc2][lo2] + redq[1][wc2][lo2];
    psum[by * H_D + n0 + tid] = s;
    psq[by * H_D + n0 + tid] = q;
  }
}

// ------------- Kernel 3: finalize BN -> scale/shift ----------------------
__global__ __launch_bounds__(256) void bn_final_kernel(
    const float* __restrict__ psum, const float* __restrict__ psq,
    const float* __restrict__ gamma, const float* __restrict__ beta,
    float* __restrict__ scale, float* __restrict__ shift) {
  const int col = blockIdx.x * 256 + threadIdx.x;
  float s = 0.f, q = 0.f;
#pragma unroll
  for (int i = 0; i < 16; ++i) {
    s += psum[i * H_D + col];
    q += psq[i * H_D + col];
  }
  const float inv_n = 1.0f / (float)B_SZ;
  float mean = s * inv_n;
  float var = q * inv_n - mean * mean;
  float rstd = rsqrtf(var + BN_EPS);
  float sc = rstd * gamma[col];
  scale[col] = sc;
  shift[col] = beta[col] - mean * sc;
}

// ------------- Kernel 4: BN apply + ReLU + classifier GEMM ----------------
__global__ __launch_bounds__(256) void clf_kernel(
    const float* __restrict__ h, const float* __restrict__ scale,
    const float* __restrict__ shift, const float* __restrict__ WT,
    const float* __restrict__ bclf, float* __restrict__ out) {
  __shared__ float v[H_D];
  const int row = blockIdx.x;
  const int tid = threadIdx.x;
#pragma unroll
  for (int i = 0; i < 4; ++i) {
    int k = tid + i * 256;
    float x = h[(size_t)row * H_D + k] * scale[k] + shift[k];
    v[k] = fmaxf(x, 0.f);
  }
  __syncthreads();
  const int wave = tid >> 6, lane = tid & 63;
  for (int j = wave; j < NCLS; j += 4) {
    const float* wrow = WT + j * H_D;
    float acc = 0.f;
#pragma unroll
    for (int i = 0; i < 16; ++i) {
      int k = lane + i * 64;
      acc += v[k] * wrow[k];
    }
#pragma unroll
    for (int off = 32; off > 0; off >>= 1) acc += __shfl_down(acc, off, 64);
    if (lane == 0) out[(size_t)row * NCLS + j] = acc + bclf[j];
  }
}

extern "C" void kernel_launch(void* const* d_in, const int* in_sizes, int n_in,
                              void* d_out, int out_size, void* d_ws, size_t ws_size,
                              hipStream_t stream) {
  const int* title = (const int*)d_in[0];
  const int* desc  = (const int*)d_in[1];
  const int* t_len = (const int*)d_in[2];
  const int* d_len = (const int*)d_in[3];
  const float* emb   = (const float*)d_in[4];
  const float* W_fc  = (const float*)d_in[5];
  const float* b_fc  = (const float*)d_in[6];
  const float* gamma = (const float*)d_in[7];
  const float* beta  = (const float*)d_in[8];
  const float* W_clf = (const float*)d_in[9];
  const float* b_clf = (const float*)d_in[10];
  float* out = (float*)d_out;

  unsigned char* ws = (unsigned char*)d_ws;
  __hip_bfloat16* swem = (__hip_bfloat16*)ws;                       // 4 MB
  __hip_bfloat16* Wt   = (__hip_bfloat16*)(ws + (4u << 20));        // 4 MB
  float* h     = (float*)(ws + (8u << 20));                         // 4 MB
  float* psum  = (float*)(ws + (12u << 20));                        // 64 KB
  float* psq   = psum + 16 * H_D;                                   // 64 KB
  float* scale = psq + 16 * H_D;                                    // 4 KB
  float* shift = scale + H_D;                                       // 4 KB
  float* WclfT = shift + H_D;                                       // 40 KB

  const int n_tr_blocks = (K_FC / 64) * (H_D / 64) + 1;  // 512 W_fc + WclfT
  pool_tr_kernel<<<2 * B_SZ + n_tr_blocks, 512, 0, stream>>>(
      title, desc, t_len, d_len, emb, swem, W_fc, Wt, W_clf, WclfT);
  gemm_mfma_kernel<<<dim3(16, 16), 512, 0, stream>>>(swem, Wt, b_fc, h, psum, psq);
  bn_final_kernel<<<H_D / 256, 256, 0, stream>>>(psum, psq, gamma, beta, scale, shift);
  clf_kernel<<<B_SZ, 256, 0, stream>>>(h, scale, shift, WclfT, b_clf, out);
}

// Round 15
// 62.699 us; speedup vs baseline: 1.0384x; 1.0384x over previous
//
#include <hip/hip_runtime.h>
#include <hip/hip_bf16.h>

#define EMB_DIM 512
#define B_SZ 1024
#define LT 50
#define LD 200
#define H_D 1024
#define K_FC 2048   // 4*EMB_DIM
#define NCLS 10
#define BN_EPS 1e-5f
#define NEGV -1e30f

typedef short short8 __attribute__((ext_vector_type(8)));
typedef float f32x4 __attribute__((ext_vector_type(4)));

// XOR swizzle: spread 128B-stride rows across banks (guide §6 G4)
#define SWZ(r, b) ((b) ^ (((r) & 7) << 4))

#define ACC4(S, M, E) \
  S.x += E.x; S.y += E.y; S.z += E.z; S.w += E.w; \
  M.x = fmaxf(M.x, E.x); M.y = fmaxf(M.y, E.y); \
  M.z = fmaxf(M.z, E.z); M.w = fmaxf(M.w, E.w);

// ---------------- Kernel 1: fused SWEM pool + transposes ------------------
// Pool: 4-stream pipelined gather (R13 version, best measured).
__global__ __launch_bounds__(512) void pool_tr_kernel(
    const int* __restrict__ title, const int* __restrict__ desc,
    const int* __restrict__ t_len, const int* __restrict__ d_len,
    const float* __restrict__ emb, __hip_bfloat16* __restrict__ swem,
    const float* __restrict__ W, __hip_bfloat16* __restrict__ Wt,
    const float* __restrict__ Wclf, float* __restrict__ WclfT) {
  __shared__ float sm[8192];
  __shared__ int idxs[264];

  const int bid = blockIdx.x;
  const int tid = threadIdx.x;

  if (bid >= 2 * B_SZ) {
    const int t = bid - 2 * B_SZ;
    if (t == 512) {
      for (int idx = tid; idx < NCLS * H_D; idx += 512) {
        int j = idx >> 10, k = idx & 1023;
        WclfT[j * H_D + k] = Wclf[(size_t)k * NCLS + j];
      }
      return;
    }
    const int n0 = (t & 15) * 64;
    const int k0 = (t >> 4) * 64;
#pragma unroll
    for (int i = 0; i < 8; ++i) {
      int idx = i * 512 + tid;
      int r = idx >> 6, c = idx & 63;
      sm[r * 65 + c] = W[(size_t)(k0 + r) * H_D + n0 + c];
    }
    __syncthreads();
#pragma unroll
    for (int i = 0; i < 8; ++i) {
      int idx = i * 512 + tid;
      int r = idx >> 6, c = idx & 63;
      Wt[(size_t)(n0 + r) * K_FC + k0 + c] = __float2bfloat16(sm[c * 65 + r]);
    }
    return;
  }

  const int b = bid >> 1;
  const int half = bid & 1;
  const int wave = tid >> 6;
  const int lane = tid & 63;
  const int dbase = half * 256 + lane * 4;

  if (tid < LT) idxs[tid] = title[b * LT + tid];
  else if (tid >= 64 && tid < 64 + LD) idxs[tid] = desc[b * LD + tid - 64];
  const int tl = t_len[b];
  const int dl = d_len[b];
  __syncthreads();

#define LOADT(IDXOFF, I) \
  (*reinterpret_cast<const float4*>(emb + (size_t)idxs[(IDXOFF) + wave + (I) * 8] * EMB_DIM + dbase))

#define POOL_LIST(LEN, IDXOFF, SARR, MARR)                                         \
  {                                                                                \
    float4 s0 = make_float4(0.f, 0.f, 0.f, 0.f), s1 = s0, s2 = s0, s3 = s0;        \
    float4 m0 = make_float4(NEGV, NEGV, NEGV, NEGV), m1 = m0, m2 = m0, m3 = m0;    \
    const int cnt = (LEN > wave) ? ((LEN - wave + 7) >> 3) : 0;                    \
    int i = 0;                                                                     \
    if (cnt >= 4) {                                                                \
      float4 e0 = LOADT(IDXOFF, 0); float4 e1 = LOADT(IDXOFF, 1);                  \
      float4 e2 = LOADT(IDXOFF, 2); float4 e3 = LOADT(IDXOFF, 3);                  \
      i = 4;                                                                       \
      for (; i + 3 < cnt; i += 4) {                                                \
        float4 q0 = LOADT(IDXOFF, i);     float4 q1 = LOADT(IDXOFF, i + 1);        \
        float4 q2 = LOADT(IDXOFF, i + 2); float4 q3 = LOADT(IDXOFF, i + 3);        \
        ACC4(s0, m0, e0); ACC4(s1, m1, e1); ACC4(s2, m2, e2); ACC4(s3, m3, e3);    \
        e0 = q0; e1 = q1; e2 = q2; e3 = q3;                                        \
      }                                                                            \
      ACC4(s0, m0, e0); ACC4(s1, m1, e1); ACC4(s2, m2, e2); ACC4(s3, m3, e3);      \
    }                                                                              \
    for (; i < cnt; ++i) { float4 t2 = LOADT(IDXOFF, i); ACC4(s0, m0, t2); }       \
    s0.x += s1.x + s2.x + s3.x; s0.y += s1.y + s2.y + s3.y;                        \
    s0.z += s1.z + s2.z + s3.z; s0.w += s1.w + s2.w + s3.w;                        \
    m0.x = fmaxf(fmaxf(m0.x, m1.x), fmaxf(m2.x, m3.x));                            \
    m0.y = fmaxf(fmaxf(m0.y, m1.y), fmaxf(m2.y, m3.y));                            \
    m0.z = fmaxf(fmaxf(m0.z, m1.z), fmaxf(m2.z, m3.z));                            \
    m0.w = fmaxf(fmaxf(m0.w, m1.w), fmaxf(m2.w, m3.w));                            \
    *reinterpret_cast<float4*>(&sm[(SARR * 8 + wave) * 256 + lane * 4]) = s0;      \
    *reinterpret_cast<float4*>(&sm[(MARR * 8 + wave) * 256 + lane * 4]) = m0;      \
  }

  POOL_LIST(tl, 0, 0, 1)
  POOL_LIST(dl, 64, 2, 3)

  __syncthreads();

  if (tid < 64) {
    const float it = 1.0f / (float)tl;
    const float id = 1.0f / (float)dl;
    float4 ts = make_float4(0.f, 0.f, 0.f, 0.f);
    float4 tm = make_float4(NEGV, NEGV, NEGV, NEGV);
    float4 ds = make_float4(0.f, 0.f, 0.f, 0.f);
    float4 dm = make_float4(NEGV, NEGV, NEGV, NEGV);
#pragma unroll
    for (int w = 0; w < 8; ++w) {
      float4 a = *reinterpret_cast<const float4*>(&sm[(0 * 8 + w) * 256 + tid * 4]);
      ts.x += a.x; ts.y += a.y; ts.z += a.z; ts.w += a.w;
      float4 bmx = *reinterpret_cast<const float4*>(&sm[(1 * 8 + w) * 256 + tid * 4]);
      tm.x = fmaxf(tm.x, bmx.x); tm.y = fmaxf(tm.y, bmx.y);
      tm.z = fmaxf(tm.z, bmx.z); tm.w = fmaxf(tm.w, bmx.w);
      float4 c = *reinterpret_cast<const float4*>(&sm[(2 * 8 + w) * 256 + tid * 4]);
      ds.x += c.x; ds.y += c.y; ds.z += c.z; ds.w += c.w;
      float4 dmx = *reinterpret_cast<const float4*>(&sm[(3 * 8 + w) * 256 + tid * 4]);
      dm.x = fmaxf(dm.x, dmx.x); dm.y = fmaxf(dm.y, dmx.y);
      dm.z = fmaxf(dm.z, dmx.z); dm.w = fmaxf(dm.w, dmx.w);
    }
    __hip_bfloat16* row = swem + (size_t)b * K_FC + half * 256 + tid * 4;
    union { ushort4 v; __hip_bfloat16 h[4]; } u;
    u.h[0] = __float2bfloat16(ts.x * it); u.h[1] = __float2bfloat16(ts.y * it);
    u.h[2] = __float2bfloat16(ts.z * it); u.h[3] = __float2bfloat16(ts.w * it);
    *reinterpret_cast<ushort4*>(&row[0 * EMB_DIM]) = u.v;
    u.h[0] = __float2bfloat16(tm.x); u.h[1] = __float2bfloat16(tm.y);
    u.h[2] = __float2bfloat16(tm.z); u.h[3] = __float2bfloat16(tm.w);
    *reinterpret_cast<ushort4*>(&row[1 * EMB_DIM]) = u.v;
    u.h[0] = __float2bfloat16(ds.x * id); u.h[1] = __float2bfloat16(ds.y * id);
    u.h[2] = __float2bfloat16(ds.z * id); u.h[3] = __float2bfloat16(ds.w * id);
    *reinterpret_cast<ushort4*>(&row[2 * EMB_DIM]) = u.v;
    u.h[0] = __float2bfloat16(dm.x); u.h[1] = __float2bfloat16(dm.y);
    u.h[2] = __float2bfloat16(dm.z); u.h[3] = __float2bfloat16(dm.w);
    *reinterpret_cast<ushort4*>(&row[3 * EMB_DIM]) = u.v;
  }
}

// ---------------- Kernel 2: MFMA GEMM (R9/R13 version, best measured) -----
// 64x64 tile, 256 blocks XCD-swizzled, 512 threads, dbuf LDS, reg prefetch 2.
__global__ __launch_bounds__(512) void gemm_mfma_kernel(
    const __hip_bfloat16* __restrict__ A,   // [1024][2048] bf16 (swem)
    const __hip_bfloat16* __restrict__ Bt,  // [1024][2048] bf16 (W_fc^T)
    const float* __restrict__ bias, float* __restrict__ C,
    float* __restrict__ psum, float* __restrict__ psq) {
  __shared__ unsigned char As[2][8192];
  __shared__ unsigned char Bs[2][8192];
  __shared__ float reds[2][4][16];  // [wr][wc][lo]
  __shared__ float redq[2][4][16];
  const int tid = threadIdx.x;
  const int lane = tid & 63;
  const int wave = tid >> 6;        // 0..7
  const int wr = wave >> 2;         // 0,1  (M)
  const int wc = wave & 3;          // 0..3 (N)

  const int lin = blockIdx.y * 16 + blockIdx.x;
  const int swzb = (lin & 7) * 32 + (lin >> 3);
  const int bx = swzb & 15, by = swzb >> 4;
  const int m0 = by * 64, n0 = bx * 64;

  f32x4 acc[2] = {};                // mi = 0,1

  const int rs = tid >> 3;          // row 0..63
  const int os = tid & 7;           // 16B slot 0..7
  const int hi = lane >> 4;
  const int lo = lane & 15;

  const __hip_bfloat16* pa = A + (size_t)(m0 + rs) * K_FC + os * 8;
  const __hip_bfloat16* pb = Bt + (size_t)(n0 + rs) * K_FC + os * 8;
  const int swz = SWZ(rs, rs * 128 + os * 16);

  float4 a1 = *reinterpret_cast<const float4*>(pa);
  float4 b1 = *reinterpret_cast<const float4*>(pb);
  *reinterpret_cast<float4*>(&As[0][swz]) = a1;
  *reinterpret_cast<float4*>(&Bs[0][swz]) = b1;
  a1 = *reinterpret_cast<const float4*>(pa + 64);
  b1 = *reinterpret_cast<const float4*>(pb + 64);
  __syncthreads();

  int cur = 0;
  for (int k0 = 0; k0 < K_FC; k0 += 64) {
    float4 an = make_float4(0.f, 0.f, 0.f, 0.f), bn = an;
    if (k0 + 128 < K_FC) {
      an = *reinterpret_cast<const float4*>(pa + k0 + 128);
      bn = *reinterpret_cast<const float4*>(pb + k0 + 128);
    }

#pragma unroll
    for (int kks = 0; kks < 2; ++kks) {
      short8 af[2];
#pragma unroll
      for (int mi = 0; mi < 2; ++mi) {
        int r = wr * 32 + mi * 16 + lo;
        af[mi] = *reinterpret_cast<const short8*>(&As[cur][SWZ(r, r * 128 + kks * 64 + hi * 16)]);
      }
      int rb = wc * 16 + lo;
      short8 bf = *reinterpret_cast<const short8*>(&Bs[cur][SWZ(rb, rb * 128 + kks * 64 + hi * 16)]);
#pragma unroll
      for (int mi = 0; mi < 2; ++mi)
        acc[mi] = __builtin_amdgcn_mfma_f32_16x16x32_bf16(af[mi], bf, acc[mi], 0, 0, 0);
    }

    if (k0 + 64 < K_FC) {
      *reinterpret_cast<float4*>(&As[cur ^ 1][swz]) = a1;
      *reinterpret_cast<float4*>(&Bs[cur ^ 1][swz]) = b1;
    }
    __syncthreads();
    a1 = an; b1 = bn;
    cur ^= 1;
  }

  // epilogue: C write (+bias) and per-column partial sum/sumsq.
  // C/D layout: col=lane&15, row=(lane>>4)*4+reg (m89-verified).
  {
    int col = n0 + wc * 16 + lo;
    float bv = bias[col];
    float s = 0.f, q = 0.f;
#pragma unroll
    for (int mi = 0; mi < 2; ++mi) {
#pragma unroll
      for (int r = 0; r < 4; ++r) {
        float v = acc[mi][r] + bv;
        s += v; q += v * v;
        int rowm = m0 + wr * 32 + mi * 16 + hi * 4 + r;
        C[(size_t)rowm * H_D + col] = v;
      }
    }
    s += __shfl_xor(s, 16);
    s += __shfl_xor(s, 32);
    q += __shfl_xor(q, 16);
    q += __shfl_xor(q, 32);
    if (lane < 16) { reds[wr][wc][lo] = s; redq[wr][wc][lo] = q; }
  }
  __syncthreads();
  if (tid < 64) {
    int wc2 = tid >> 4, lo2 = tid & 15;
    float s = reds[0][wc2][lo2] + reds[1][wc2][lo2];
    float q = redq[0][wc2][lo2] + redq[1][wc2][lo2];
    psum[by * H_D + n0 + tid] = s;
    psq[by * H_D + n0 + tid] = q;
  }
}

// ------------- Kernel 3: finalize BN -> scale/shift ----------------------
__global__ __launch_bounds__(256) void bn_final_kernel(
    const float* __restrict__ psum, const float* __restrict__ psq,
    const float* __restrict__ gamma, const float* __restrict__ beta,
    float* __restrict__ scale, float* __restrict__ shift) {
  const int col = blockIdx.x * 256 + threadIdx.x;
  float s = 0.f, q = 0.f;
#pragma unroll
  for (int i = 0; i < 16; ++i) {
    s += psum[i * H_D + col];
    q += psq[i * H_D + col];
  }
  const float inv_n = 1.0f / (float)B_SZ;
  float mean = s * inv_n;
  float var = q * inv_n - mean * mean;
  float rstd = rsqrtf(var + BN_EPS);
  float sc = rstd * gamma[col];
  scale[col] = sc;
  shift[col] = beta[col] - mean * sc;
}

// ------------- Kernel 4: BN apply + ReLU + classifier GEMM ----------------
__global__ __launch_bounds__(256) void clf_kernel(
    const float* __restrict__ h, const float* __restrict__ scale,
    const float* __restrict__ shift, const float* __restrict__ WT,
    const float* __restrict__ bclf, float* __restrict__ out) {
  __shared__ float v[H_D];
  const int row = blockIdx.x;
  const int tid = threadIdx.x;
#pragma unroll
  for (int i = 0; i < 4; ++i) {
    int k = tid + i * 256;
    float x = h[(size_t)row * H_D + k] * scale[k] + shift[k];
    v[k] = fmaxf(x, 0.f);
  }
  __syncthreads();
  const int wave = tid >> 6, lane = tid & 63;
  for (int j = wave; j < NCLS; j += 4) {
    const float* wrow = WT + j * H_D;
    float acc = 0.f;
#pragma unroll
    for (int i = 0; i < 16; ++i) {
      int k = lane + i * 64;
      acc += v[k] * wrow[k];
    }
#pragma unroll
    for (int off = 32; off > 0; off >>= 1) acc += __shfl_down(acc, off, 64);
    if (lane == 0) out[(size_t)row * NCLS + j] = acc + bclf[j];
  }
}

extern "C" void kernel_launch(void* const* d_in, const int* in_sizes, int n_in,
                              void* d_out, int out_size, void* d_ws, size_t ws_size,
                              hipStream_t stream) {
  const int* title = (const int*)d_in[0];
  const int* desc  = (const int*)d_in[1];
  const int* t_len = (const int*)d_in[2];
  const int* d_len = (const int*)d_in[3];
  const float* emb   = (const float*)d_in[4];
  const float* W_fc  = (const float*)d_in[5];
  const float* b_fc  = (const float*)d_in[6];
  const float* gamma = (const float*)d_in[7];
  const float* beta  = (const float*)d_in[8];
  const float* W_clf = (const float*)d_in[9];
  const float* b_clf = (const float*)d_in[10];
  float* out = (float*)d_out;

  unsigned char* ws = (unsigned char*)d_ws;
  __hip_bfloat16* swem = (__hip_bfloat16*)ws;                       // 4 MB
  __hip_bfloat16* Wt   = (__hip_bfloat16*)(ws + (4u << 20));        // 4 MB
  float* h     = (float*)(ws + (8u << 20));                         // 4 MB
  float* psum  = (float*)(ws + (12u << 20));                        // 64 KB
  float* psq   = psum + 16 * H_D;                                   // 64 KB
  float* scale = psq + 16 * H_D;                                    // 4 KB
  float* shift = scale + H_D;                                       // 4 KB
  float* WclfT = shift + H_D;                                       // 40 KB

  const int n_tr_blocks = (K_FC / 64) * (H_D / 64) + 1;  // 512 W_fc + WclfT
  pool_tr_kernel<<<2 * B_SZ + n_tr_blocks, 512, 0, stream>>>(
      title, desc, t_len, d_len, emb, swem, W_fc, Wt, W_clf, WclfT);
  gemm_mfma_kernel<<<dim3(16, 16), 512, 0, stream>>>(swem, Wt, b_fc, h, psum, psq);
  bn_final_kernel<<<H_D / 256, 256, 0, stream>>>(psum, psq, gamma, beta, scale, shift);
  clf_kernel<<<B_SZ, 256, 0, stream>>>(h, scale, shift, WclfT, b_clf, out);
}